// Round 12
// baseline (465.946 us; speedup 1.0000x reference)
//
#include <hip/hip_runtime.h>

#define NN   50000      // nodes
#define NF   64         // input features
#define NDIM 128        // hidden / output dim
#define NE   600000     // edges
#define NM   3          // graphs
#define NTOT (NN * NDIM)
#define PTRSZ (NN + 1)
#define CH    2048                      // edges per sort block
#define B1    ((NE + CH - 1) / CH)      // 293 sort blocks per m
#define NBKT  ((NN + 255) / 256)        // 196 column buckets
#define BB    200                       // bktBase row stride
#define NSC   (NBKT * B1)               // 57428 scan elements per m

typedef __attribute__((ext_vector_type(8))) short short8;
typedef __attribute__((ext_vector_type(4))) float f32x4;
typedef __attribute__((ext_vector_type(4))) unsigned int u32x4;
typedef unsigned long long u64;

__device__ __forceinline__ unsigned short f2bf(float x) {
    unsigned int u = __float_as_uint(x);
    return (unsigned short)((u + 0x7FFFu + ((u >> 16) & 1u)) >> 16);  // RNE
}
__device__ __forceinline__ float blo(unsigned int u) { return __uint_as_float(u << 16); }
__device__ __forceinline__ float bhi(unsigned int u) { return __uint_as_float(u & 0xFFFF0000u); }

// ---------------------------------------------------------------- fused prep + histA:
// stat zero + bf16 weight transposes + bf16 feature cast + sort histogram, one launch
#define PREPW_EXT 73728                 // 8192 + 16384 + 49152
#define PREP_NB   ((PREPW_EXT + NM * NN * 32) / 256)   // 19038 (exact)
__global__ void k_prep_hist(const float* __restrict__ w1, const float* __restrict__ w2,
                            const float* __restrict__ cnnw, const float* __restrict__ feat,
                            const int* __restrict__ adj,
                            unsigned short* __restrict__ w1t, unsigned short* __restrict__ w2t,
                            unsigned short* __restrict__ wcb, unsigned int* __restrict__ fb,
                            float* __restrict__ stat, int* __restrict__ counts) {
    __shared__ int hist[NBKT];
    if (blockIdx.x < PREP_NB) {
        int i = blockIdx.x * 256 + threadIdx.x;
        if (i < 6 * 256 + 8) stat[i] = 0.f;
        if (i < 8192) {
            int n = i >> 6, k = i & 63;
            w1t[i] = f2bf(w1[k * 128 + n]);
        } else if (i < 8192 + 16384) {
            int j = i - 8192;
            int n = j >> 7, k = j & 127;
            w2t[j] = f2bf(w2[k * 128 + n]);
        } else if (i < PREPW_EXT) {
            int j = i - 24576;
            wcb[j] = f2bf(cnnw[j]);
        }
        int j = i - PREPW_EXT;
        if (j >= 0 && j < NM * NN * 32) {
            float2 v = reinterpret_cast<const float2*>(feat)[j];
            fb[j] = (unsigned int)f2bf(v.x) | ((unsigned int)f2bf(v.y) << 16);
        }
    } else {
        const int bb = blockIdx.x - PREP_NB;
        const int m = bb / B1, b = bb - m * B1, tid = threadIdx.x;
        for (int k = tid; k < NBKT; k += 256) hist[k] = 0;
        __syncthreads();
        const int* col = adj + m * 2 * NE + NE;
        int e0 = b * CH;
#pragma unroll
        for (int i = 0; i < CH / 256; ++i) {
            int e = e0 + i * 256 + tid;
            if (e < NE) atomicAdd(&hist[col[e] >> 8], 1);
        }
        __syncthreads();
        for (int k = tid; k < NBKT; k += 256) counts[m * NSC + k * B1 + b] = hist[k];
    }
}

// ---------------------------------------------------------------- sort phase B1: per-bucket local scan (in place) + totals
__global__ void k_scanB1(int* __restrict__ counts, int* __restrict__ bktTot) {
    const int bkt = blockIdx.x, m = blockIdx.y, t = threadIdx.x;
    int* cp = counts + m * NSC + bkt * B1;
    __shared__ int part[256];
    int i0 = t * 2;
    int v0 = (i0 < B1) ? cp[i0] : 0;
    int v1 = (i0 + 1 < B1) ? cp[i0 + 1] : 0;
    int s = v0 + v1;
    part[t] = s;
    __syncthreads();
    for (int off = 1; off < 256; off <<= 1) {
        int x = (t >= off) ? part[t - off] : 0;
        __syncthreads();
        part[t] += x;
        __syncthreads();
    }
    int run = part[t] - s;   // exclusive over pairs
    if (i0 < B1) cp[i0] = run;
    if (i0 + 1 < B1) cp[i0 + 1] = run + v0;
    if (t == 255) bktTot[m * BB + bkt] = part[255];
}

// ---------------------------------------------------------------- sort phase B2: scan bucket totals -> bktBase
__global__ void k_scanB2(const int* __restrict__ bktTot, int* __restrict__ bktBase) {
    const int m = blockIdx.x, t = threadIdx.x;
    __shared__ int part[256];
    int v = (t < NBKT) ? bktTot[m * BB + t] : 0;
    part[t] = v;
    __syncthreads();
    for (int off = 1; off < 256; off <<= 1) {
        int x = (t >= off) ? part[t - off] : 0;
        __syncthreads();
        part[t] += x;
        __syncthreads();
    }
    if (t < NBKT) bktBase[m * BB + t] = part[t] - v;
    if (t == 0) bktBase[m * BB + NBKT] = NE;
}

// ---------------------------------------------------------------- sort phase C: scatter into bucket-grouped ebkt (NT store)
__global__ void k_scatC(const int* __restrict__ adj, const float* __restrict__ ew,
                        const int* __restrict__ counts, const int* __restrict__ bktBase,
                        int2* __restrict__ ebkt) {
    const int m = blockIdx.y, b = blockIdx.x, tid = threadIdx.x;
    __shared__ int tick[NBKT];
    for (int k = tid; k < NBKT; k += 256) tick[k] = 0;
    __syncthreads();
    const int* rowp = adj + m * 2 * NE;
    const int* colp = rowp + NE;
    const float* ewm = ew + (size_t)m * NE;
    int e0 = b * CH;
#pragma unroll
    for (int i = 0; i < CH / 256; ++i) {
        int e = e0 + i * 256 + tid;
        if (e < NE) {
            unsigned int c = (unsigned int)colp[e];
            unsigned int r = (unsigned int)rowp[e];
            int bkt = c >> 8;
            int tk = atomicAdd(&tick[bkt], 1);
            int pos = bktBase[m * BB + bkt] + counts[m * NSC + bkt * B1 + b] + tk;
            u64 pv = (u64)(r | (c << 16)) | ((u64)(unsigned int)__float_as_int(ewm[e]) << 32);
            __builtin_nontemporal_store(pv, (u64*)&ebkt[(size_t)m * NE + pos]);
        }
    }
}

// ---------------------------------------------------------------- sort phase D1a: per-bucket stats (NT ebkt load)
__global__ void k_finD1a(const int2* __restrict__ ebkt, const int* __restrict__ bktBase,
                         float* __restrict__ dis, int* __restrict__ ptr) {
    const int bkt = blockIdx.x, m = blockIdx.y, tid = threadIdx.x;
    const int j0 = bktBase[m * BB + bkt], j1 = bktBase[m * BB + bkt + 1];
    __shared__ int cnt[256];
    __shared__ unsigned int degfp[256];
    __shared__ int coff[256];
    cnt[tid] = 0; degfp[tid] = 0;
    __syncthreads();
    const int2* eb = ebkt + (size_t)m * NE;
    for (int j = j0 + tid; j < j1; j += 256) {
        u64 v = __builtin_nontemporal_load((const u64*)&eb[j]);
        unsigned int vx = (unsigned int)v;
        int clow = (int)((vx >> 16) & 255u);
        atomicAdd(&cnt[clow], 1);
        atomicAdd(&degfp[clow], (unsigned int)(__uint_as_float((unsigned int)(v >> 32)) * 262144.0f));
    }
    __syncthreads();
    int c = bkt * 256 + tid;
    if (c < NN) dis[m * NN + c] = rsqrtf(1.0f + (float)degfp[tid] * (1.0f / 262144.0f));
    // exclusive scan of cnt
    int s = cnt[tid];
    coff[tid] = s;
    __syncthreads();
    for (int off = 1; off < 256; off <<= 1) {
        int v = (tid >= off) ? coff[tid - off] : 0;
        __syncthreads();
        coff[tid] += v;
        __syncthreads();
    }
    if (c < NN) ptr[m * PTRSZ + c] = j0 + coff[tid] - s;
    if (bkt == NBKT - 1 && tid == 0) ptr[m * PTRSZ + NN] = NE;
}

// ---------------------------------------------------------------- sort phase D1b: permute with norm fused (NT in/out)
__global__ void k_finD1b(const int2* __restrict__ ebkt, const int* __restrict__ bktBase,
                         const float* __restrict__ disB, const int* __restrict__ ptrB,
                         int2* __restrict__ epack) {
    const int bkt = blockIdx.x, m = blockIdx.y, tid = threadIdx.x;
    const int j0 = bktBase[m * BB + bkt], j1 = bktBase[m * BB + bkt + 1];
    __shared__ int pbase[256];
    __shared__ int tick[256];
    __shared__ float sdc[256];
    int c = bkt * 256 + tid;
    pbase[tid] = (c < NN) ? ptrB[m * PTRSZ + c] : 0;
    sdc[tid] = (c < NN) ? disB[m * NN + c] : 0.f;
    tick[tid] = 0;
    __syncthreads();
    const int2* eb = ebkt + (size_t)m * NE;
    const float* disb = disB + m * NN;
    int2* ep = epack + (size_t)m * NE;
    for (int j = j0 + tid; j < j1; j += 256) {
        u64 v = __builtin_nontemporal_load((const u64*)&eb[j]);
        unsigned int w0 = (unsigned int)v;
        int r = (int)(w0 & 0xFFFFu);
        int clow = (int)((w0 >> 16) & 255u);
        int t = atomicAdd(&tick[clow], 1);
        float nrm = __uint_as_float((unsigned int)(v >> 32)) * disb[r] * sdc[clow];
        u64 pv = (u64)(unsigned int)r | ((u64)(unsigned int)__float_as_int(nrm) << 32);
        __builtin_nontemporal_store(pv, (u64*)&ep[pbase[clow] + t]);
    }
}

// ---------------------------------------------------------------- MFMA GEMM (batched over m)
// out_bf[n,o] = bf16( sum_k A[n,k]*W[k,o] ); BN: relu((a-mean)*invstd) fold on A-load.
template<int K, bool ABF16, bool BN>
__global__ __launch_bounds__(256, 2) void k_mgemm(const void* __restrict__ Abase,
                                                  const unsigned short* __restrict__ Wt,
                                                  const float* __restrict__ statB,
                                                  unsigned short* __restrict__ outB) {
    __shared__ unsigned short sA[128 * 72];
    __shared__ unsigned short sB[128 * 72];
    __shared__ float smi[256];
    const int m = blockIdx.y;
    const float* Af = (const float*)Abase + (size_t)m * NN * K;
    const unsigned int* Au = (const unsigned int*)Abase + (size_t)m * NN * (K / 2);
    unsigned short* outb = outB + (size_t)m * NTOT;
    const int tid = threadIdx.x;
    const int lane = tid & 63, wave = tid >> 6;
    const int llo = lane & 15, lhi = lane >> 4;
    const int row0 = blockIdx.x * 128;
    const int waveR0 = wave * 32;
    const unsigned int* Wtu = reinterpret_cast<const unsigned int*>(Wt);
    if (BN) {
        const float* stat = statB + m * 256;
        if (tid < 128) {
            float mean = stat[tid] * (1.f / (float)NN);
            float var = stat[128 + tid] * (1.f / (float)NN) - mean * mean;
            smi[tid] = mean;
            smi[128 + tid] = rsqrtf(var + 1e-5f);
        }
        __syncthreads();
    }
    f32x4 acc[2][8];
#pragma unroll
    for (int i = 0; i < 2; ++i)
#pragma unroll
        for (int t = 0; t < 8; ++t) acc[i][t] = (f32x4){0.f, 0.f, 0.f, 0.f};

    for (int ch = 0; ch < K / 64; ++ch) {
        const int kc0 = ch * 64;
        for (int idx = tid; idx < 4096; idx += 256) {
            int r = idx >> 5, kk2 = idx & 31;
            int g = row0 + r;
            float vx = 0.f, vy = 0.f;
            if (g < NN) {
                if (ABF16) {
                    unsigned int u = Au[(size_t)g * (K / 2) + kc0 / 2 + kk2];
                    vx = blo(u); vy = bhi(u);
                } else {
                    float2 v = *reinterpret_cast<const float2*>(Af + (size_t)g * K + kc0 + kk2 * 2);
                    vx = v.x; vy = v.y;
                }
                if (BN) {
                    int d0 = kc0 + kk2 * 2;
                    vx = fmaxf((vx - smi[d0]) * smi[128 + d0], 0.f);
                    vy = fmaxf((vy - smi[d0 + 1]) * smi[128 + d0 + 1], 0.f);
                }
            }
            reinterpret_cast<unsigned int*>(sA)[r * 36 + kk2] =
                (unsigned int)f2bf(vx) | ((unsigned int)f2bf(vy) << 16);
        }
        for (int idx = tid; idx < 4096; idx += 256) {
            int n = idx >> 5, kk2 = idx & 31;
            reinterpret_cast<unsigned int*>(sB)[n * 36 + kk2] =
                Wtu[n * (K / 2) + kc0 / 2 + kk2];
        }
        __syncthreads();
#pragma unroll
        for (int ks = 0; ks < 64; ks += 32) {
            short8 a0 = *reinterpret_cast<const short8*>(sA + (waveR0 + llo) * 72 + ks + lhi * 8);
            short8 a1 = *reinterpret_cast<const short8*>(sA + (waveR0 + 16 + llo) * 72 + ks + lhi * 8);
#pragma unroll
            for (int t = 0; t < 8; ++t) {
                short8 b = *reinterpret_cast<const short8*>(sB + (t * 16 + llo) * 72 + ks + lhi * 8);
                acc[0][t] = __builtin_amdgcn_mfma_f32_16x16x32_bf16(a0, b, acc[0][t], 0, 0, 0);
                acc[1][t] = __builtin_amdgcn_mfma_f32_16x16x32_bf16(a1, b, acc[1][t], 0, 0, 0);
            }
        }
        __syncthreads();
    }
#pragma unroll
    for (int rt = 0; rt < 2; ++rt)
#pragma unroll
        for (int r = 0; r < 4; ++r) {
            int grow = row0 + waveR0 + rt * 16 + lhi * 4 + r;
            if (grow < NN) {
#pragma unroll
                for (int t = 0; t < 8; ++t)
                    outb[(size_t)grow * NDIM + t * 16 + llo] = f2bf(acc[rt][t][r]);
            }
        }
}

// ---------------------------------------------------------------- CSR gather (bf16 rows, uint4 lanes, 2-edge ILP)
// NT: epack loads + output stores (stream-once); xq row gathers stay cached.
template<int KB>
__global__ void k_gather(const unsigned short* __restrict__ xwB, const float* __restrict__ disB,
                         const int* __restrict__ ptrB, const int2* __restrict__ epackB,
                         unsigned short* __restrict__ outB) {
    constexpr int L = KB / 8;          // uint4 lanes per row (16B each)
    constexpr int NPB = 256 / L;       // nodes per block
    const int m = blockIdx.y;
    const uint4* xq = reinterpret_cast<const uint4*>(xwB + (size_t)m * NN * KB);
    const int* ptr = ptrB + m * PTRSZ;
    const int2* epack = epackB + (size_t)m * NE;
    int sub = threadIdx.x / L;
    int lane = threadIdx.x & (L - 1);
    int c = blockIdx.x * NPB + sub;
    if (c >= NN) return;
    float ds = disB[m * NN + c];
    float s2 = ds * ds;
    uint4 sv = xq[(size_t)c * L + lane];
    float a0 = blo(sv.x) * s2, a1 = bhi(sv.x) * s2;
    float a2 = blo(sv.y) * s2, a3 = bhi(sv.y) * s2;
    float a4 = blo(sv.z) * s2, a5 = bhi(sv.z) * s2;
    float a6 = blo(sv.w) * s2, a7 = bhi(sv.w) * s2;
    float b0 = 0.f, b1 = 0.f, b2 = 0.f, b3 = 0.f;
    float b4 = 0.f, b5 = 0.f, b6 = 0.f, b7 = 0.f;
    int j = ptr[c], j1 = ptr[c + 1];
    for (; j + 1 < j1; j += 2) {
        u64 e0 = __builtin_nontemporal_load((const u64*)&epack[j]);
        u64 e1 = __builtin_nontemporal_load((const u64*)&epack[j + 1]);
        int r0i = (int)(unsigned int)e0, r1i = (int)(unsigned int)e1;
        uint4 r0 = xq[(size_t)r0i * L + lane];
        uint4 r1 = xq[(size_t)r1i * L + lane];
        float n0 = __uint_as_float((unsigned int)(e0 >> 32));
        float n1 = __uint_as_float((unsigned int)(e1 >> 32));
        a0 = fmaf(blo(r0.x), n0, a0); a1 = fmaf(bhi(r0.x), n0, a1);
        a2 = fmaf(blo(r0.y), n0, a2); a3 = fmaf(bhi(r0.y), n0, a3);
        a4 = fmaf(blo(r0.z), n0, a4); a5 = fmaf(bhi(r0.z), n0, a5);
        a6 = fmaf(blo(r0.w), n0, a6); a7 = fmaf(bhi(r0.w), n0, a7);
        b0 = fmaf(blo(r1.x), n1, b0); b1 = fmaf(bhi(r1.x), n1, b1);
        b2 = fmaf(blo(r1.y), n1, b2); b3 = fmaf(bhi(r1.y), n1, b3);
        b4 = fmaf(blo(r1.z), n1, b4); b5 = fmaf(bhi(r1.z), n1, b5);
        b6 = fmaf(blo(r1.w), n1, b6); b7 = fmaf(bhi(r1.w), n1, b7);
    }
    if (j < j1) {
        u64 e0 = __builtin_nontemporal_load((const u64*)&epack[j]);
        int r0i = (int)(unsigned int)e0;
        uint4 r0 = xq[(size_t)r0i * L + lane];
        float n0 = __uint_as_float((unsigned int)(e0 >> 32));
        a0 = fmaf(blo(r0.x), n0, a0); a1 = fmaf(bhi(r0.x), n0, a1);
        a2 = fmaf(blo(r0.y), n0, a2); a3 = fmaf(bhi(r0.y), n0, a3);
        a4 = fmaf(blo(r0.z), n0, a4); a5 = fmaf(bhi(r0.z), n0, a5);
        a6 = fmaf(blo(r0.w), n0, a6); a7 = fmaf(bhi(r0.w), n0, a7);
    }
    u32x4 res;
    res.x = (unsigned int)f2bf(a0 + b0) | ((unsigned int)f2bf(a1 + b1) << 16);
    res.y = (unsigned int)f2bf(a2 + b2) | ((unsigned int)f2bf(a3 + b3) << 16);
    res.z = (unsigned int)f2bf(a4 + b4) | ((unsigned int)f2bf(a5 + b5) << 16);
    res.w = (unsigned int)f2bf(a6 + b6) | ((unsigned int)f2bf(a7 + b7) << 16);
    __builtin_nontemporal_store(res,
        (u32x4*)(outB + (size_t)m * NN * KB) + (size_t)c * L + lane);
}

// ---------------------------------------------------------------- BatchNorm stats, vectorized (NT uint4, few atomics)
__global__ void k_bnstatsV(const unsigned short* __restrict__ xB, float* __restrict__ statB) {
    const int m = blockIdx.y;
    const u32x4* xq = reinterpret_cast<const u32x4*>(xB + (size_t)m * NTOT);
    float* stat = statB + m * 256;
    const int lane = threadIdx.x & 15, sub = threadIdx.x >> 4;
    float s[8] = {0.f, 0.f, 0.f, 0.f, 0.f, 0.f, 0.f, 0.f};
    float q[8] = {0.f, 0.f, 0.f, 0.f, 0.f, 0.f, 0.f, 0.f};
    for (int n = blockIdx.x * 16 + sub; n < NN; n += gridDim.x * 16) {
        u32x4 u = __builtin_nontemporal_load(&xq[(size_t)n * 16 + lane]);
        float v;
        v = blo(u.x); s[0] += v; q[0] = fmaf(v, v, q[0]);
        v = bhi(u.x); s[1] += v; q[1] = fmaf(v, v, q[1]);
        v = blo(u.y); s[2] += v; q[2] = fmaf(v, v, q[2]);
        v = bhi(u.y); s[3] += v; q[3] = fmaf(v, v, q[3]);
        v = blo(u.z); s[4] += v; q[4] = fmaf(v, v, q[4]);
        v = bhi(u.z); s[5] += v; q[5] = fmaf(v, v, q[5]);
        v = blo(u.w); s[6] += v; q[6] = fmaf(v, v, q[6]);
        v = bhi(u.w); s[7] += v; q[7] = fmaf(v, v, q[7]);
    }
    __shared__ float sd[16][264];
#pragma unroll
    for (int k = 0; k < 8; ++k) {
        sd[sub][lane * 8 + k] = s[k];
        sd[sub][128 + lane * 8 + k] = q[k];
    }
    __syncthreads();
    float tot = 0.f;
#pragma unroll
    for (int ss = 0; ss < 16; ++ss) tot += sd[ss][threadIdx.x];
    atomicAdd(&stat[threadIdx.x], tot);
}

// sum of relu((x-mean)*invstd), vectorized NT; (mean,invstd) from stats in-block
__global__ void k_bnsumV(const unsigned short* __restrict__ xB, const float* __restrict__ statB,
                         float* __restrict__ ssum) {
    const int m = blockIdx.y;
    const u32x4* xq = reinterpret_cast<const u32x4*>(xB + (size_t)m * NTOT);
    __shared__ float smi[256];
    {
        const float* stat = statB + m * 256;
        if (threadIdx.x < 128) {
            float mean = stat[threadIdx.x] * (1.f / (float)NN);
            float var = stat[128 + threadIdx.x] * (1.f / (float)NN) - mean * mean;
            smi[threadIdx.x] = mean;
            smi[128 + threadIdx.x] = rsqrtf(var + 1e-5f);
        }
        __syncthreads();
    }
    const int lane = threadIdx.x & 15, sub = threadIdx.x >> 4;
    const int c0 = lane * 8;
    float local = 0.f;
    for (int n = blockIdx.x * 16 + sub; n < NN; n += gridDim.x * 16) {
        u32x4 u = __builtin_nontemporal_load(&xq[(size_t)n * 16 + lane]);
        local += fmaxf((blo(u.x) - smi[c0 + 0]) * smi[128 + c0 + 0], 0.f)
               + fmaxf((bhi(u.x) - smi[c0 + 1]) * smi[128 + c0 + 1], 0.f)
               + fmaxf((blo(u.y) - smi[c0 + 2]) * smi[128 + c0 + 2], 0.f)
               + fmaxf((bhi(u.y) - smi[c0 + 3]) * smi[128 + c0 + 3], 0.f)
               + fmaxf((blo(u.z) - smi[c0 + 4]) * smi[128 + c0 + 4], 0.f)
               + fmaxf((bhi(u.z) - smi[c0 + 5]) * smi[128 + c0 + 5], 0.f)
               + fmaxf((blo(u.w) - smi[c0 + 6]) * smi[128 + c0 + 6], 0.f)
               + fmaxf((bhi(u.w) - smi[c0 + 7]) * smi[128 + c0 + 7], 0.f);
    }
    __shared__ float red[256];
    red[threadIdx.x] = local;
    __syncthreads();
    for (int s = 128; s > 0; s >>= 1) {
        if (threadIdx.x < s) red[threadIdx.x] += red[threadIdx.x + s];
        __syncthreads();
    }
    if (threadIdx.x == 0) atomicAdd(&ssum[m], red[0]);
}

// ---------------------------------------------------------------- final MFMA GEMM (K=384, BN+SE-y fold, +bias)
__global__ __launch_bounds__(256, 2) void k_mfinal(const unsigned short* __restrict__ xB,
                                                   const float* __restrict__ statB,
                                                   const unsigned short* __restrict__ wcb,
                                                   const float* __restrict__ ssum,
                                                   const float* __restrict__ fc1w,
                                                   const float* __restrict__ fc1b,
                                                   const float* __restrict__ fc2w,
                                                   const float* __restrict__ fc2b,
                                                   const float* __restrict__ cnnb,
                                                   float* __restrict__ out) {
    __shared__ unsigned short sA[128 * 72];
    __shared__ unsigned short sB[128 * 72];
    __shared__ float smi[768];
    __shared__ float ysh[NM];
    const int tid = threadIdx.x;
    const int lane = tid & 63, wave = tid >> 6;
    const int llo = lane & 15, lhi = lane >> 4;
    const int row0 = blockIdx.x * 128;
    const int waveR0 = wave * 32;
    const unsigned int* Wtu = reinterpret_cast<const unsigned int*>(wcb);
    if (tid == 0) {
        float sv[NM], h[6 * NM];
        for (int mm = 0; mm < NM; ++mm) sv[mm] = ssum[mm] * (1.f / (float)NTOT);
        for (int jj = 0; jj < 6 * NM; ++jj) {
            float a = fc1b[jj];
            for (int mm = 0; mm < NM; ++mm) a = fmaf(sv[mm], fc1w[jj * NM + mm], a);
            h[jj] = fmaxf(a, 0.f);
        }
        for (int mm = 0; mm < NM; ++mm) {
            float a = fc2b[mm];
            for (int jj = 0; jj < 6 * NM; ++jj) a = fmaf(h[jj], fc2w[mm * 6 * NM + jj], a);
            ysh[mm] = 1.f / (1.f + expf(-a));
        }
    }
    for (int t = tid; t < 384; t += 256) {
        int mm = t >> 7, d = t & 127;
        const float* stat = statB + mm * 256;
        float mean = stat[d] * (1.f / (float)NN);
        float var = stat[128 + d] * (1.f / (float)NN) - mean * mean;
        smi[mm * 256 + d] = mean;
        smi[mm * 256 + 128 + d] = rsqrtf(var + 1e-5f);
    }
    __syncthreads();
    f32x4 acc[2][8];
#pragma unroll
    for (int i = 0; i < 2; ++i)
#pragma unroll
        for (int t = 0; t < 8; ++t) acc[i][t] = (f32x4){0.f, 0.f, 0.f, 0.f};

#pragma unroll
    for (int ch = 0; ch < 6; ++ch) {
        const int m = ch >> 1;
        const int dbase = (ch & 1) * 64;
        const unsigned int* Au = reinterpret_cast<const unsigned int*>(xB + (size_t)m * NTOT);
        const float* mi = smi + m * 256;
        const float ym = ysh[m];
        for (int idx = tid; idx < 4096; idx += 256) {
            int r = idx >> 5, kk2 = idx & 31;
            int g = row0 + r;
            float vx = 0.f, vy = 0.f;
            if (g < NN) {
                unsigned int u = Au[(size_t)g * 64 + dbase / 2 + kk2];
                int c = dbase + kk2 * 2;
                vx = fmaxf((blo(u) - mi[c]) * mi[128 + c], 0.f) * ym;
                vy = fmaxf((bhi(u) - mi[c + 1]) * mi[129 + c], 0.f) * ym;
            }
            reinterpret_cast<unsigned int*>(sA)[r * 36 + kk2] =
                (unsigned int)f2bf(vx) | ((unsigned int)f2bf(vy) << 16);
        }
        for (int idx = tid; idx < 4096; idx += 256) {
            int n = idx >> 5, kk2 = idx & 31;
            reinterpret_cast<unsigned int*>(sB)[n * 36 + kk2] = Wtu[n * 192 + ch * 32 + kk2];
        }
        __syncthreads();
#pragma unroll
        for (int ks = 0; ks < 64; ks += 32) {
            short8 a0 = *reinterpret_cast<const short8*>(sA + (waveR0 + llo) * 72 + ks + lhi * 8);
            short8 a1 = *reinterpret_cast<const short8*>(sA + (waveR0 + 16 + llo) * 72 + ks + lhi * 8);
#pragma unroll
            for (int t = 0; t < 8; ++t) {
                short8 b = *reinterpret_cast<const short8*>(sB + (t * 16 + llo) * 72 + ks + lhi * 8);
                acc[0][t] = __builtin_amdgcn_mfma_f32_16x16x32_bf16(a0, b, acc[0][t], 0, 0, 0);
                acc[1][t] = __builtin_amdgcn_mfma_f32_16x16x32_bf16(a1, b, acc[1][t], 0, 0, 0);
            }
        }
        __syncthreads();
    }
#pragma unroll
    for (int rt = 0; rt < 2; ++rt)
#pragma unroll
        for (int r = 0; r < 4; ++r) {
            int grow = row0 + waveR0 + rt * 16 + lhi * 4 + r;
            if (grow < NN) {
#pragma unroll
                for (int t = 0; t < 8; ++t)
                    out[(size_t)grow * NDIM + t * 16 + llo] = acc[rt][t][r] + cnnb[t * 16 + llo];
            }
        }
}

// ================================================================ launch
extern "C" void kernel_launch(void* const* d_in, const int* in_sizes, int n_in,
                              void* d_out, int out_size, void* d_ws, size_t ws_size,
                              hipStream_t stream) {
    const float* feat = (const float*)d_in[0];   // [3,50000,64]
    const int*   adj  = (const int*)d_in[1];     // [3,2,600000]
    const float* ew   = (const float*)d_in[2];   // [3,600000]
    const float* w1   = (const float*)d_in[3];   // [64,128]
    const float* w2   = (const float*)d_in[5];   // [128,128]
    const float* fc1w = (const float*)d_in[7];   // [18,3]
    const float* fc1b = (const float*)d_in[8];   // [18]
    const float* fc2w = (const float*)d_in[9];   // [3,18]
    const float* fc2b = (const float*)d_in[10];  // [3]
    const float* cnnw = (const float*)d_in[11];  // [128,3,128,1] == [128][384]
    const float* cnnb = (const float*)d_in[12];  // [128]
    float* out = (float*)d_out;

    float* ws = (float*)d_ws;
    size_t off = 0;
    float* bufA = ws + off; off += NM * NTOT / 2;   // fb(19.2MB) -> z1 -> agg2   (bf16 space)
    float* bufB = ws + off; off += NM * NTOT / 2;   // agg1(19.2MB) -> z2         (bf16 space)
    int2*  epack = (int2*)(ws + off); off += NM * NE * 2;
    int2*  ebkt  = (int2*)(ws + off); off += NM * NE * 2;
    float* dis  = ws + off; off += NM * NN;
    int*   ptr  = (int*)(ws + off); off += NM * PTRSZ + 13;
    int*   counts = (int*)(ws + off); off += NM * NSC;
    int*   bktTot  = (int*)(ws + off); off += NM * BB + 8;
    int*   bktBase = (int*)(ws + off); off += NM * BB + 8;
    float* stat6 = ws + off; off += 6 * 256;
    float* ssum = ws + off; off += 8;               // zeroed with stat6
    unsigned short* w1t = (unsigned short*)(ws + off); off += 8192 / 2;
    unsigned short* w2t = (unsigned short*)(ws + off); off += 16384 / 2;
    unsigned short* wcb = (unsigned short*)(ws + off); off += 49152 / 2;

    unsigned short* fbA  = (unsigned short*)bufA;   // bf16 feat [m][N][64]
    unsigned short* agg1 = (unsigned short*)bufB;   // bf16 agg  [m][N][64]
    unsigned short* z1   = (unsigned short*)bufA;   // bf16 [m][N][128]
    unsigned short* z2   = (unsigned short*)bufB;   // bf16 [m][N][128]
    unsigned short* agg2 = (unsigned short*)bufA;   // bf16 [m][N][128]

    const int GB = (NN + 127) / 128;   // 391
    dim3 gGemm(GB, NM), gSort(B1, NM), gD1(NBKT, NM);
    dim3 gGath1((NN + 31) / 32, NM), gGath2((NN + 15) / 16, NM);
    dim3 gStat(128, NM);

    // fused prep (+histA): stat zero + weight transposes + feature cast + sort histogram
    k_prep_hist<<<PREP_NB + B1 * NM, 256, 0, stream>>>(
        w1, w2, cnnw, feat, adj, w1t, w2t, wcb, (unsigned int*)fbA, stat6, counts);

    // CSR build: two-level LDS counting sort (no global atomics); norm fused in D1b
    k_scanB1<<<gD1, 256, 0, stream>>>(counts, bktTot);
    k_scanB2<<<NM, 256, 0, stream>>>(bktTot, bktBase);
    k_scatC<<<gSort, 256, 0, stream>>>(adj, ew, counts, bktBase, ebkt);
    k_finD1a<<<gD1, 256, 0, stream>>>(ebkt, bktBase, dis, ptr);
    k_finD1b<<<gD1, 256, 0, stream>>>(ebkt, bktBase, dis, ptr, epack);

    // layer 1: aggregate X (64-wide) first, then @W1   [(A·X)·W1 == A·(X·W1)]
    k_gather<64><<<gGath1, 256, 0, stream>>>(fbA, dis, ptr, epack, agg1);
    k_mgemm<64, true, false><<<gGemm, 256, 0, stream>>>(agg1, w1t, nullptr, z1);
    k_bnstatsV<<<gStat, 256, 0, stream>>>(z1, stat6);

    // layer 2: BN(relu)@W2 -> gather -> stats -> SE sums
    k_mgemm<NDIM, true, true><<<gGemm, 256, 0, stream>>>(z1, w2t, stat6, z2);
    k_gather<128><<<gGath2, 256, 0, stream>>>(z2, dis, ptr, epack, agg2);
    k_bnstatsV<<<gStat, 256, 0, stream>>>(agg2, stat6 + NM * 256);
    k_bnsumV<<<gStat, 256, 0, stream>>>(agg2, stat6 + NM * 256, ssum);

    // final fused GEMM (SE-y computed in-kernel)
    k_mfinal<<<GB, 256, 0, stream>>>(agg2, stat6 + NM * 256, wcb, ssum,
                                     fc1w, fc1b, fc2w, fc2b, cnnb, out);
}

// Round 13
// 330.481 us; speedup vs baseline: 1.4099x; 1.4099x over previous
//
#include <hip/hip_runtime.h>

#define NN   50000      // nodes
#define NF   64         // input features
#define NDIM 128        // hidden / output dim
#define NE   600000     // edges
#define NM   3          // graphs
#define NTOT (NN * NDIM)
#define PTRSZ (NN + 1)
#define CH    2048                      // edges per sort block
#define B1    ((NE + CH - 1) / CH)      // 293 sort blocks per m
#define NBKT  ((NN + 255) / 256)        // 196 column buckets
#define BB    200                       // bktBase row stride
#define NSC   (NBKT * B1)               // 57428 scan elements per m

typedef __attribute__((ext_vector_type(8))) short short8;
typedef __attribute__((ext_vector_type(4))) float f32x4;

__device__ __forceinline__ unsigned short f2bf(float x) {
    unsigned int u = __float_as_uint(x);
    return (unsigned short)((u + 0x7FFFu + ((u >> 16) & 1u)) >> 16);  // RNE
}
__device__ __forceinline__ float blo(unsigned int u) { return __uint_as_float(u << 16); }
__device__ __forceinline__ float bhi(unsigned int u) { return __uint_as_float(u & 0xFFFF0000u); }

// ---------------------------------------------------------------- fused prep:
// stat zero + bf16 weight transposes + bf16 feature cast, one launch
#define PREPW_EXT 73728                 // 8192 + 16384 + 49152
__global__ void k_prep(const float* __restrict__ w1, const float* __restrict__ w2,
                       const float* __restrict__ cnnw, const float* __restrict__ feat,
                       unsigned short* __restrict__ w1t, unsigned short* __restrict__ w2t,
                       unsigned short* __restrict__ wcb, unsigned int* __restrict__ fb,
                       float* __restrict__ stat) {
    int i = blockIdx.x * 256 + threadIdx.x;
    if (i < 6 * 256 + 8) stat[i] = 0.f;
    if (i < 8192) {
        int n = i >> 6, k = i & 63;
        w1t[i] = f2bf(w1[k * 128 + n]);
    } else if (i < 8192 + 16384) {
        int j = i - 8192;
        int n = j >> 7, k = j & 127;
        w2t[j] = f2bf(w2[k * 128 + n]);
    } else if (i < PREPW_EXT) {
        int j = i - 24576;
        wcb[j] = f2bf(cnnw[j]);
    }
    int j = i - PREPW_EXT;
    if (j >= 0 && j < NM * NN * 32) {
        float2 v = reinterpret_cast<const float2*>(feat)[j];
        fb[j] = (unsigned int)f2bf(v.x) | ((unsigned int)f2bf(v.y) << 16);
    }
}

// ---------------------------------------------------------------- sort phase A: per-(block,bucket) counts
__global__ void k_histA(const int* __restrict__ adj, int* __restrict__ counts) {
    const int m = blockIdx.y, b = blockIdx.x, tid = threadIdx.x;
    __shared__ int hist[NBKT];
    for (int k = tid; k < NBKT; k += 256) hist[k] = 0;
    __syncthreads();
    const int* col = adj + m * 2 * NE + NE;
    int e0 = b * CH;
#pragma unroll
    for (int i = 0; i < CH / 256; ++i) {
        int e = e0 + i * 256 + tid;
        if (e < NE) atomicAdd(&hist[col[e] >> 8], 1);
    }
    __syncthreads();
    for (int k = tid; k < NBKT; k += 256) counts[m * NSC + k * B1 + b] = hist[k];
}

// ---------------------------------------------------------------- sort phase B1: per-bucket local scan (in place) + totals
__global__ void k_scanB1(int* __restrict__ counts, int* __restrict__ bktTot) {
    const int bkt = blockIdx.x, m = blockIdx.y, t = threadIdx.x;
    int* cp = counts + m * NSC + bkt * B1;
    __shared__ int part[256];
    int i0 = t * 2;
    int v0 = (i0 < B1) ? cp[i0] : 0;
    int v1 = (i0 + 1 < B1) ? cp[i0 + 1] : 0;
    int s = v0 + v1;
    part[t] = s;
    __syncthreads();
    for (int off = 1; off < 256; off <<= 1) {
        int x = (t >= off) ? part[t - off] : 0;
        __syncthreads();
        part[t] += x;
        __syncthreads();
    }
    int run = part[t] - s;   // exclusive over pairs
    if (i0 < B1) cp[i0] = run;
    if (i0 + 1 < B1) cp[i0 + 1] = run + v0;
    if (t == 255) bktTot[m * BB + bkt] = part[255];
}

// ---------------------------------------------------------------- sort phase B2: scan bucket totals -> bktBase
__global__ void k_scanB2(const int* __restrict__ bktTot, int* __restrict__ bktBase) {
    const int m = blockIdx.x, t = threadIdx.x;
    __shared__ int part[256];
    int v = (t < NBKT) ? bktTot[m * BB + t] : 0;
    part[t] = v;
    __syncthreads();
    for (int off = 1; off < 256; off <<= 1) {
        int x = (t >= off) ? part[t - off] : 0;
        __syncthreads();
        part[t] += x;
        __syncthreads();
    }
    if (t < NBKT) bktBase[m * BB + t] = part[t] - v;
    if (t == 0) bktBase[m * BB + NBKT] = NE;
}

// ---------------------------------------------------------------- sort phase C: scatter into bucket-grouped ebkt
__global__ void k_scatC(const int* __restrict__ adj, const float* __restrict__ ew,
                        const int* __restrict__ counts, const int* __restrict__ bktBase,
                        int2* __restrict__ ebkt) {
    const int m = blockIdx.y, b = blockIdx.x, tid = threadIdx.x;
    __shared__ int tick[NBKT];
    for (int k = tid; k < NBKT; k += 256) tick[k] = 0;
    __syncthreads();
    const int* rowp = adj + m * 2 * NE;
    const int* colp = rowp + NE;
    const float* ewm = ew + (size_t)m * NE;
    int e0 = b * CH;
#pragma unroll
    for (int i = 0; i < CH / 256; ++i) {
        int e = e0 + i * 256 + tid;
        if (e < NE) {
            unsigned int c = (unsigned int)colp[e];
            unsigned int r = (unsigned int)rowp[e];
            int bkt = c >> 8;
            int tk = atomicAdd(&tick[bkt], 1);
            int pos = bktBase[m * BB + bkt] + counts[m * NSC + bkt * B1 + b] + tk;
            ebkt[(size_t)m * NE + pos] = make_int2((int)(r | (c << 16)), __float_as_int(ewm[e]));
        }
    }
}

// ---------------------------------------------------------------- sort phase D1a: per-bucket stats
// per-column count + fixed-point degree (LDS) -> dis, ptr
__global__ void k_finD1a(const int2* __restrict__ ebkt, const int* __restrict__ bktBase,
                         float* __restrict__ dis, int* __restrict__ ptr) {
    const int bkt = blockIdx.x, m = blockIdx.y, tid = threadIdx.x;
    const int j0 = bktBase[m * BB + bkt], j1 = bktBase[m * BB + bkt + 1];
    __shared__ int cnt[256];
    __shared__ unsigned int degfp[256];
    __shared__ int coff[256];
    cnt[tid] = 0; degfp[tid] = 0;
    __syncthreads();
    const int2* eb = ebkt + (size_t)m * NE;
    for (int j = j0 + tid; j < j1; j += 256) {
        int2 v = eb[j];
        int clow = (int)(((unsigned int)v.x >> 16) & 255u);
        atomicAdd(&cnt[clow], 1);
        atomicAdd(&degfp[clow], (unsigned int)(__int_as_float(v.y) * 262144.0f));
    }
    __syncthreads();
    int c = bkt * 256 + tid;
    if (c < NN) dis[m * NN + c] = rsqrtf(1.0f + (float)degfp[tid] * (1.0f / 262144.0f));
    // exclusive scan of cnt
    int s = cnt[tid];
    coff[tid] = s;
    __syncthreads();
    for (int off = 1; off < 256; off <<= 1) {
        int v = (tid >= off) ? coff[tid - off] : 0;
        __syncthreads();
        coff[tid] += v;
        __syncthreads();
    }
    if (c < NN) ptr[m * PTRSZ + c] = j0 + coff[tid] - s;
    if (bkt == NBKT - 1 && tid == 0) ptr[m * PTRSZ + NN] = NE;
}

// ---------------------------------------------------------------- sort phase D1b: permute with norm fused
// epack[pos] = (r, ew*dis[r]*dis[c]); dis[c]/ptr[c] from LDS, dis[r] via L2
__global__ void k_finD1b(const int2* __restrict__ ebkt, const int* __restrict__ bktBase,
                         const float* __restrict__ disB, const int* __restrict__ ptrB,
                         int2* __restrict__ epack) {
    const int bkt = blockIdx.x, m = blockIdx.y, tid = threadIdx.x;
    const int j0 = bktBase[m * BB + bkt], j1 = bktBase[m * BB + bkt + 1];
    __shared__ int pbase[256];
    __shared__ int tick[256];
    __shared__ float sdc[256];
    int c = bkt * 256 + tid;
    pbase[tid] = (c < NN) ? ptrB[m * PTRSZ + c] : 0;
    sdc[tid] = (c < NN) ? disB[m * NN + c] : 0.f;
    tick[tid] = 0;
    __syncthreads();
    const int2* eb = ebkt + (size_t)m * NE;
    const float* disb = disB + m * NN;
    int2* ep = epack + (size_t)m * NE;
    for (int j = j0 + tid; j < j1; j += 256) {
        int2 v = eb[j];
        unsigned int w0 = (unsigned int)v.x;
        int r = (int)(w0 & 0xFFFFu);
        int clow = (int)((w0 >> 16) & 255u);
        int t = atomicAdd(&tick[clow], 1);
        float nrm = __int_as_float(v.y) * disb[r] * sdc[clow];
        ep[pbase[clow] + t] = make_int2(r, __float_as_int(nrm));
    }
}

// ---------------------------------------------------------------- MFMA GEMM (batched over m)
// out_bf[n,o] = bf16( sum_k A[n,k]*W[k,o] ); BN: relu((a-mean)*invstd) fold on A-load.
template<int K, bool ABF16, bool BN>
__global__ __launch_bounds__(256, 2) void k_mgemm(const void* __restrict__ Abase,
                                                  const unsigned short* __restrict__ Wt,
                                                  const float* __restrict__ statB,
                                                  unsigned short* __restrict__ outB) {
    __shared__ unsigned short sA[128 * 72];
    __shared__ unsigned short sB[128 * 72];
    __shared__ float smi[256];
    const int m = blockIdx.y;
    const float* Af = (const float*)Abase + (size_t)m * NN * K;
    const unsigned int* Au = (const unsigned int*)Abase + (size_t)m * NN * (K / 2);
    unsigned short* outb = outB + (size_t)m * NTOT;
    const int tid = threadIdx.x;
    const int lane = tid & 63, wave = tid >> 6;
    const int llo = lane & 15, lhi = lane >> 4;
    const int row0 = blockIdx.x * 128;
    const int waveR0 = wave * 32;
    const unsigned int* Wtu = reinterpret_cast<const unsigned int*>(Wt);
    if (BN) {
        const float* stat = statB + m * 256;
        if (tid < 128) {
            float mean = stat[tid] * (1.f / (float)NN);
            float var = stat[128 + tid] * (1.f / (float)NN) - mean * mean;
            smi[tid] = mean;
            smi[128 + tid] = rsqrtf(var + 1e-5f);
        }
        __syncthreads();
    }
    f32x4 acc[2][8];
#pragma unroll
    for (int i = 0; i < 2; ++i)
#pragma unroll
        for (int t = 0; t < 8; ++t) acc[i][t] = (f32x4){0.f, 0.f, 0.f, 0.f};

    for (int ch = 0; ch < K / 64; ++ch) {
        const int kc0 = ch * 64;
        for (int idx = tid; idx < 4096; idx += 256) {
            int r = idx >> 5, kk2 = idx & 31;
            int g = row0 + r;
            float vx = 0.f, vy = 0.f;
            if (g < NN) {
                if (ABF16) {
                    unsigned int u = Au[(size_t)g * (K / 2) + kc0 / 2 + kk2];
                    vx = blo(u); vy = bhi(u);
                } else {
                    float2 v = *reinterpret_cast<const float2*>(Af + (size_t)g * K + kc0 + kk2 * 2);
                    vx = v.x; vy = v.y;
                }
                if (BN) {
                    int d0 = kc0 + kk2 * 2;
                    vx = fmaxf((vx - smi[d0]) * smi[128 + d0], 0.f);
                    vy = fmaxf((vy - smi[d0 + 1]) * smi[128 + d0 + 1], 0.f);
                }
            }
            reinterpret_cast<unsigned int*>(sA)[r * 36 + kk2] =
                (unsigned int)f2bf(vx) | ((unsigned int)f2bf(vy) << 16);
        }
        for (int idx = tid; idx < 4096; idx += 256) {
            int n = idx >> 5, kk2 = idx & 31;
            reinterpret_cast<unsigned int*>(sB)[n * 36 + kk2] =
                Wtu[n * (K / 2) + kc0 / 2 + kk2];
        }
        __syncthreads();
#pragma unroll
        for (int ks = 0; ks < 64; ks += 32) {
            short8 a0 = *reinterpret_cast<const short8*>(sA + (waveR0 + llo) * 72 + ks + lhi * 8);
            short8 a1 = *reinterpret_cast<const short8*>(sA + (waveR0 + 16 + llo) * 72 + ks + lhi * 8);
#pragma unroll
            for (int t = 0; t < 8; ++t) {
                short8 b = *reinterpret_cast<const short8*>(sB + (t * 16 + llo) * 72 + ks + lhi * 8);
                acc[0][t] = __builtin_amdgcn_mfma_f32_16x16x32_bf16(a0, b, acc[0][t], 0, 0, 0);
                acc[1][t] = __builtin_amdgcn_mfma_f32_16x16x32_bf16(a1, b, acc[1][t], 0, 0, 0);
            }
        }
        __syncthreads();
    }
#pragma unroll
    for (int rt = 0; rt < 2; ++rt)
#pragma unroll
        for (int r = 0; r < 4; ++r) {
            int grow = row0 + waveR0 + rt * 16 + lhi * 4 + r;
            if (grow < NN) {
#pragma unroll
                for (int t = 0; t < 8; ++t)
                    outb[(size_t)grow * NDIM + t * 16 + llo] = f2bf(acc[rt][t][r]);
            }
        }
}

// ---------------------------------------------------------------- CSR gather (bf16 rows, uint4 lanes, 2-edge ILP)
template<int KB>
__global__ void k_gather(const unsigned short* __restrict__ xwB, const float* __restrict__ disB,
                         const int* __restrict__ ptrB, const int2* __restrict__ epackB,
                         unsigned short* __restrict__ outB) {
    constexpr int L = KB / 8;          // uint4 lanes per row (16B each)
    constexpr int NPB = 256 / L;       // nodes per block
    const int m = blockIdx.y;
    const uint4* xq = reinterpret_cast<const uint4*>(xwB + (size_t)m * NN * KB);
    const int* ptr = ptrB + m * PTRSZ;
    const int2* epack = epackB + (size_t)m * NE;
    int sub = threadIdx.x / L;
    int lane = threadIdx.x & (L - 1);
    int c = blockIdx.x * NPB + sub;
    if (c >= NN) return;
    float ds = disB[m * NN + c];
    float s2 = ds * ds;
    uint4 sv = xq[(size_t)c * L + lane];
    float a0 = blo(sv.x) * s2, a1 = bhi(sv.x) * s2;
    float a2 = blo(sv.y) * s2, a3 = bhi(sv.y) * s2;
    float a4 = blo(sv.z) * s2, a5 = bhi(sv.z) * s2;
    float a6 = blo(sv.w) * s2, a7 = bhi(sv.w) * s2;
    float b0 = 0.f, b1 = 0.f, b2 = 0.f, b3 = 0.f;
    float b4 = 0.f, b5 = 0.f, b6 = 0.f, b7 = 0.f;
    int j = ptr[c], j1 = ptr[c + 1];
    for (; j + 1 < j1; j += 2) {
        int2 e0 = epack[j], e1 = epack[j + 1];
        uint4 r0 = xq[(size_t)e0.x * L + lane];
        uint4 r1 = xq[(size_t)e1.x * L + lane];
        float n0 = __int_as_float(e0.y), n1 = __int_as_float(e1.y);
        a0 = fmaf(blo(r0.x), n0, a0); a1 = fmaf(bhi(r0.x), n0, a1);
        a2 = fmaf(blo(r0.y), n0, a2); a3 = fmaf(bhi(r0.y), n0, a3);
        a4 = fmaf(blo(r0.z), n0, a4); a5 = fmaf(bhi(r0.z), n0, a5);
        a6 = fmaf(blo(r0.w), n0, a6); a7 = fmaf(bhi(r0.w), n0, a7);
        b0 = fmaf(blo(r1.x), n1, b0); b1 = fmaf(bhi(r1.x), n1, b1);
        b2 = fmaf(blo(r1.y), n1, b2); b3 = fmaf(bhi(r1.y), n1, b3);
        b4 = fmaf(blo(r1.z), n1, b4); b5 = fmaf(bhi(r1.z), n1, b5);
        b6 = fmaf(blo(r1.w), n1, b6); b7 = fmaf(bhi(r1.w), n1, b7);
    }
    if (j < j1) {
        int2 e0 = epack[j];
        uint4 r0 = xq[(size_t)e0.x * L + lane];
        float n0 = __int_as_float(e0.y);
        a0 = fmaf(blo(r0.x), n0, a0); a1 = fmaf(bhi(r0.x), n0, a1);
        a2 = fmaf(blo(r0.y), n0, a2); a3 = fmaf(bhi(r0.y), n0, a3);
        a4 = fmaf(blo(r0.z), n0, a4); a5 = fmaf(bhi(r0.z), n0, a5);
        a6 = fmaf(blo(r0.w), n0, a6); a7 = fmaf(bhi(r0.w), n0, a7);
    }
    uint4 res;
    res.x = (unsigned int)f2bf(a0 + b0) | ((unsigned int)f2bf(a1 + b1) << 16);
    res.y = (unsigned int)f2bf(a2 + b2) | ((unsigned int)f2bf(a3 + b3) << 16);
    res.z = (unsigned int)f2bf(a4 + b4) | ((unsigned int)f2bf(a5 + b5) << 16);
    res.w = (unsigned int)f2bf(a6 + b6) | ((unsigned int)f2bf(a7 + b7) << 16);
    reinterpret_cast<uint4*>(outB + (size_t)m * NN * KB)[(size_t)c * L + lane] = res;
}

// ---------------------------------------------------------------- BatchNorm stats, vectorized (uint4, few atomics)
__global__ void k_bnstatsV(const unsigned short* __restrict__ xB, float* __restrict__ statB) {
    const int m = blockIdx.y;
    const uint4* xq = reinterpret_cast<const uint4*>(xB + (size_t)m * NTOT);
    float* stat = statB + m * 256;
    const int lane = threadIdx.x & 15, sub = threadIdx.x >> 4;
    float s[8] = {0.f, 0.f, 0.f, 0.f, 0.f, 0.f, 0.f, 0.f};
    float q[8] = {0.f, 0.f, 0.f, 0.f, 0.f, 0.f, 0.f, 0.f};
    for (int n = blockIdx.x * 16 + sub; n < NN; n += gridDim.x * 16) {
        uint4 u = xq[(size_t)n * 16 + lane];
        float v;
        v = blo(u.x); s[0] += v; q[0] = fmaf(v, v, q[0]);
        v = bhi(u.x); s[1] += v; q[1] = fmaf(v, v, q[1]);
        v = blo(u.y); s[2] += v; q[2] = fmaf(v, v, q[2]);
        v = bhi(u.y); s[3] += v; q[3] = fmaf(v, v, q[3]);
        v = blo(u.z); s[4] += v; q[4] = fmaf(v, v, q[4]);
        v = bhi(u.z); s[5] += v; q[5] = fmaf(v, v, q[5]);
        v = blo(u.w); s[6] += v; q[6] = fmaf(v, v, q[6]);
        v = bhi(u.w); s[7] += v; q[7] = fmaf(v, v, q[7]);
    }
    __shared__ float sd[16][264];
#pragma unroll
    for (int k = 0; k < 8; ++k) {
        sd[sub][lane * 8 + k] = s[k];
        sd[sub][128 + lane * 8 + k] = q[k];
    }
    __syncthreads();
    float tot = 0.f;
#pragma unroll
    for (int ss = 0; ss < 16; ++ss) tot += sd[ss][threadIdx.x];
    atomicAdd(&stat[threadIdx.x], tot);
}

// sum of relu((x-mean)*invstd), vectorized; (mean,invstd) from stats in-block
__global__ void k_bnsumV(const unsigned short* __restrict__ xB, const float* __restrict__ statB,
                         float* __restrict__ ssum) {
    const int m = blockIdx.y;
    const uint4* xq = reinterpret_cast<const uint4*>(xB + (size_t)m * NTOT);
    __shared__ float smi[256];
    {
        const float* stat = statB + m * 256;
        if (threadIdx.x < 128) {
            float mean = stat[threadIdx.x] * (1.f / (float)NN);
            float var = stat[128 + threadIdx.x] * (1.f / (float)NN) - mean * mean;
            smi[threadIdx.x] = mean;
            smi[128 + threadIdx.x] = rsqrtf(var + 1e-5f);
        }
        __syncthreads();
    }
    const int lane = threadIdx.x & 15, sub = threadIdx.x >> 4;
    const int c0 = lane * 8;
    float local = 0.f;
    for (int n = blockIdx.x * 16 + sub; n < NN; n += gridDim.x * 16) {
        uint4 u = xq[(size_t)n * 16 + lane];
        local += fmaxf((blo(u.x) - smi[c0 + 0]) * smi[128 + c0 + 0], 0.f)
               + fmaxf((bhi(u.x) - smi[c0 + 1]) * smi[128 + c0 + 1], 0.f)
               + fmaxf((blo(u.y) - smi[c0 + 2]) * smi[128 + c0 + 2], 0.f)
               + fmaxf((bhi(u.y) - smi[c0 + 3]) * smi[128 + c0 + 3], 0.f)
               + fmaxf((blo(u.z) - smi[c0 + 4]) * smi[128 + c0 + 4], 0.f)
               + fmaxf((bhi(u.z) - smi[c0 + 5]) * smi[128 + c0 + 5], 0.f)
               + fmaxf((blo(u.w) - smi[c0 + 6]) * smi[128 + c0 + 6], 0.f)
               + fmaxf((bhi(u.w) - smi[c0 + 7]) * smi[128 + c0 + 7], 0.f);
    }
    __shared__ float red[256];
    red[threadIdx.x] = local;
    __syncthreads();
    for (int s = 128; s > 0; s >>= 1) {
        if (threadIdx.x < s) red[threadIdx.x] += red[threadIdx.x + s];
        __syncthreads();
    }
    if (threadIdx.x == 0) atomicAdd(&ssum[m], red[0]);
}

// ---------------------------------------------------------------- final MFMA GEMM (K=384, BN+SE-y fold, +bias)
// y[3] computed in-kernel by thread 0 (L2-cached ssum/fc weights)
__global__ __launch_bounds__(256, 2) void k_mfinal(const unsigned short* __restrict__ xB,
                                                   const float* __restrict__ statB,
                                                   const unsigned short* __restrict__ wcb,
                                                   const float* __restrict__ ssum,
                                                   const float* __restrict__ fc1w,
                                                   const float* __restrict__ fc1b,
                                                   const float* __restrict__ fc2w,
                                                   const float* __restrict__ fc2b,
                                                   const float* __restrict__ cnnb,
                                                   float* __restrict__ out) {
    __shared__ unsigned short sA[128 * 72];
    __shared__ unsigned short sB[128 * 72];
    __shared__ float smi[768];
    __shared__ float ysh[NM];
    const int tid = threadIdx.x;
    const int lane = tid & 63, wave = tid >> 6;
    const int llo = lane & 15, lhi = lane >> 4;
    const int row0 = blockIdx.x * 128;
    const int waveR0 = wave * 32;
    const unsigned int* Wtu = reinterpret_cast<const unsigned int*>(wcb);
    if (tid == 0) {
        float sv[NM], h[6 * NM];
        for (int mm = 0; mm < NM; ++mm) sv[mm] = ssum[mm] * (1.f / (float)NTOT);
        for (int jj = 0; jj < 6 * NM; ++jj) {
            float a = fc1b[jj];
            for (int mm = 0; mm < NM; ++mm) a = fmaf(sv[mm], fc1w[jj * NM + mm], a);
            h[jj] = fmaxf(a, 0.f);
        }
        for (int mm = 0; mm < NM; ++mm) {
            float a = fc2b[mm];
            for (int jj = 0; jj < 6 * NM; ++jj) a = fmaf(h[jj], fc2w[mm * 6 * NM + jj], a);
            ysh[mm] = 1.f / (1.f + expf(-a));
        }
    }
    for (int t = tid; t < 384; t += 256) {
        int mm = t >> 7, d = t & 127;
        const float* stat = statB + mm * 256;
        float mean = stat[d] * (1.f / (float)NN);
        float var = stat[128 + d] * (1.f / (float)NN) - mean * mean;
        smi[mm * 256 + d] = mean;
        smi[mm * 256 + 128 + d] = rsqrtf(var + 1e-5f);
    }
    __syncthreads();
    f32x4 acc[2][8];
#pragma unroll
    for (int i = 0; i < 2; ++i)
#pragma unroll
        for (int t = 0; t < 8; ++t) acc[i][t] = (f32x4){0.f, 0.f, 0.f, 0.f};

#pragma unroll
    for (int ch = 0; ch < 6; ++ch) {
        const int m = ch >> 1;
        const int dbase = (ch & 1) * 64;
        const unsigned int* Au = reinterpret_cast<const unsigned int*>(xB + (size_t)m * NTOT);
        const float* mi = smi + m * 256;
        const float ym = ysh[m];
        for (int idx = tid; idx < 4096; idx += 256) {
            int r = idx >> 5, kk2 = idx & 31;
            int g = row0 + r;
            float vx = 0.f, vy = 0.f;
            if (g < NN) {
                unsigned int u = Au[(size_t)g * 64 + dbase / 2 + kk2];
                int c = dbase + kk2 * 2;
                vx = fmaxf((blo(u) - mi[c]) * mi[128 + c], 0.f) * ym;
                vy = fmaxf((bhi(u) - mi[c + 1]) * mi[129 + c], 0.f) * ym;
            }
            reinterpret_cast<unsigned int*>(sA)[r * 36 + kk2] =
                (unsigned int)f2bf(vx) | ((unsigned int)f2bf(vy) << 16);
        }
        for (int idx = tid; idx < 4096; idx += 256) {
            int n = idx >> 5, kk2 = idx & 31;
            reinterpret_cast<unsigned int*>(sB)[n * 36 + kk2] = Wtu[n * 192 + ch * 32 + kk2];
        }
        __syncthreads();
#pragma unroll
        for (int ks = 0; ks < 64; ks += 32) {
            short8 a0 = *reinterpret_cast<const short8*>(sA + (waveR0 + llo) * 72 + ks + lhi * 8);
            short8 a1 = *reinterpret_cast<const short8*>(sA + (waveR0 + 16 + llo) * 72 + ks + lhi * 8);
#pragma unroll
            for (int t = 0; t < 8; ++t) {
                short8 b = *reinterpret_cast<const short8*>(sB + (t * 16 + llo) * 72 + ks + lhi * 8);
                acc[0][t] = __builtin_amdgcn_mfma_f32_16x16x32_bf16(a0, b, acc[0][t], 0, 0, 0);
                acc[1][t] = __builtin_amdgcn_mfma_f32_16x16x32_bf16(a1, b, acc[1][t], 0, 0, 0);
            }
        }
        __syncthreads();
    }
#pragma unroll
    for (int rt = 0; rt < 2; ++rt)
#pragma unroll
        for (int r = 0; r < 4; ++r) {
            int grow = row0 + waveR0 + rt * 16 + lhi * 4 + r;
            if (grow < NN) {
#pragma unroll
                for (int t = 0; t < 8; ++t)
                    out[(size_t)grow * NDIM + t * 16 + llo] = acc[rt][t][r] + cnnb[t * 16 + llo];
            }
        }
}

// ================================================================ launch
extern "C" void kernel_launch(void* const* d_in, const int* in_sizes, int n_in,
                              void* d_out, int out_size, void* d_ws, size_t ws_size,
                              hipStream_t stream) {
    const float* feat = (const float*)d_in[0];   // [3,50000,64]
    const int*   adj  = (const int*)d_in[1];     // [3,2,600000]
    const float* ew   = (const float*)d_in[2];   // [3,600000]
    const float* w1   = (const float*)d_in[3];   // [64,128]
    const float* w2   = (const float*)d_in[5];   // [128,128]
    const float* fc1w = (const float*)d_in[7];   // [18,3]
    const float* fc1b = (const float*)d_in[8];   // [18]
    const float* fc2w = (const float*)d_in[9];   // [3,18]
    const float* fc2b = (const float*)d_in[10];  // [3]
    const float* cnnw = (const float*)d_in[11];  // [128,3,128,1] == [128][384]
    const float* cnnb = (const float*)d_in[12];  // [128]
    float* out = (float*)d_out;

    float* ws = (float*)d_ws;
    size_t off = 0;
    float* bufA = ws + off; off += NM * NTOT / 2;   // fb(19.2MB) -> z1 -> agg2   (bf16 space)
    float* bufB = ws + off; off += NM * NTOT / 2;   // agg1(19.2MB) -> z2         (bf16 space)
    int2*  epack = (int2*)(ws + off); off += NM * NE * 2;
    int2*  ebkt  = (int2*)(ws + off); off += NM * NE * 2;
    float* dis  = ws + off; off += NM * NN;
    int*   ptr  = (int*)(ws + off); off += NM * PTRSZ + 13;
    int*   counts = (int*)(ws + off); off += NM * NSC;
    int*   bktTot  = (int*)(ws + off); off += NM * BB + 8;
    int*   bktBase = (int*)(ws + off); off += NM * BB + 8;
    float* stat6 = ws + off; off += 6 * 256;
    float* ssum = ws + off; off += 8;               // zeroed with stat6
    unsigned short* w1t = (unsigned short*)(ws + off); off += 8192 / 2;
    unsigned short* w2t = (unsigned short*)(ws + off); off += 16384 / 2;
    unsigned short* wcb = (unsigned short*)(ws + off); off += 49152 / 2;

    unsigned short* fbA  = (unsigned short*)bufA;   // bf16 feat [m][N][64]
    unsigned short* agg1 = (unsigned short*)bufB;   // bf16 agg  [m][N][64]
    unsigned short* z1   = (unsigned short*)bufA;   // bf16 [m][N][128]
    unsigned short* z2   = (unsigned short*)bufB;   // bf16 [m][N][128]
    unsigned short* agg2 = (unsigned short*)bufA;   // bf16 [m][N][128]

    const int GB = (NN + 127) / 128;   // 391
    dim3 gGemm(GB, NM), gSort(B1, NM), gD1(NBKT, NM);
    dim3 gGath1((NN + 31) / 32, NM), gGath2((NN + 15) / 16, NM);
    dim3 gStat(128, NM);

    // fused prep: stat zero + weight transposes + feature bf16 cast
    k_prep<<<(PREPW_EXT + NM * NN * 32 + 255) / 256, 256, 0, stream>>>(
        w1, w2, cnnw, feat, w1t, w2t, wcb, (unsigned int*)fbA, stat6);

    // CSR build: two-level LDS counting sort (no global atomics); norm fused in D1b
    k_histA<<<gSort, 256, 0, stream>>>(adj, counts);
    k_scanB1<<<gD1, 256, 0, stream>>>(counts, bktTot);
    k_scanB2<<<NM, 256, 0, stream>>>(bktTot, bktBase);
    k_scatC<<<gSort, 256, 0, stream>>>(adj, ew, counts, bktBase, ebkt);
    k_finD1a<<<gD1, 256, 0, stream>>>(ebkt, bktBase, dis, ptr);
    k_finD1b<<<gD1, 256, 0, stream>>>(ebkt, bktBase, dis, ptr, epack);

    // layer 1: aggregate X (64-wide) first, then @W1   [(A·X)·W1 == A·(X·W1)]
    k_gather<64><<<gGath1, 256, 0, stream>>>(fbA, dis, ptr, epack, agg1);
    k_mgemm<64, true, false><<<gGemm, 256, 0, stream>>>(agg1, w1t, nullptr, z1);
    k_bnstatsV<<<gStat, 256, 0, stream>>>(z1, stat6);

    // layer 2: BN(relu)@W2 -> gather -> stats -> SE sums
    k_mgemm<NDIM, true, true><<<gGemm, 256, 0, stream>>>(z1, w2t, stat6, z2);
    k_gather<128><<<gGath2, 256, 0, stream>>>(z2, dis, ptr, epack, agg2);
    k_bnstatsV<<<gStat, 256, 0, stream>>>(agg2, stat6 + NM * 256);
    k_bnsumV<<<gStat, 256, 0, stream>>>(agg2, stat6 + NM * 256, ssum);

    // final fused GEMM (SE-y computed in-kernel)
    k_mfinal<<<GB, 256, 0, stream>>>(agg2, stat6 + NM * 256, wcb, ssum,
                                     fc1w, fc1b, fc2w, fc2b, cnnb, out);
}